// Round 11
// baseline (160.485 us; speedup 1.0000x reference)
//
#include <hip/hip_runtime.h>

typedef unsigned short u16;
typedef unsigned int u32;

typedef __attribute__((ext_vector_type(8))) short bf16x8;
typedef __attribute__((ext_vector_type(4))) float f32x4;

#define BSH 8          // bucket shift: 256 nodes per bucket
#define CAP 5120       // staging capacity per bucket (mean 4081 at E=800k, +16 sigma)
#define OVFCAP 8192
#define CHUNK 2048     // edges per binA2 block

__device__ __forceinline__ float bf2f(u16 u) {
    return __uint_as_float(((u32)u) << 16);
}
__device__ __forceinline__ u16 f2bf(float f) {
    u32 x = __float_as_uint(f);
    return (u16)((x + 0x7fffu + ((x >> 16) & 1u)) >> 16);
}

// block-uniform dtype flag: true if x is bf16, false if fp32.
__device__ __forceinline__ bool block_isbf(const u16* __restrict__ x, float* sflag) {
    int tid = threadIdx.x;
    if (tid < 64) {
        u16 v = x[tid * 2];
        u32 ex = (v >> 7) & 0xFFu;
        unsigned long long m = __ballot(ex >= 90u && ex <= 140u);
        if (tid == 0) *sflag = (m == ~0ull) ? 1.0f : 0.0f;
    }
    __syncthreads();
    return *sflag != 0.0f;
}

__device__ __forceinline__ void acc8(uint4 w, float* a) {
    a[0] += bf2f((u16)(w.x & 0xFFFFu)); a[1] += bf2f((u16)(w.x >> 16));
    a[2] += bf2f((u16)(w.y & 0xFFFFu)); a[3] += bf2f((u16)(w.y >> 16));
    a[4] += bf2f((u16)(w.z & 0xFFFFu)); a[5] += bf2f((u16)(w.z >> 16));
    a[6] += bf2f((u16)(w.w & 0xFFFFu)); a[7] += bf2f((u16)(w.w >> 16));
}

// Bin edges into per-bucket staging. NO per-node atomics. bucket(d) = d >> BSH.
// Packed entry: src | (d & 255) << 16.
__global__ __launch_bounds__(256) void k_binA2(
    const int* __restrict__ src, const int* __restrict__ dst,
    int* __restrict__ gcur, u32* __restrict__ staging,
    u32* __restrict__ ovf, int* __restrict__ ovfcur, int E) {
    __shared__ int hcnt[256];
    __shared__ int hbase[256];
    const int tid = threadIdx.x;
    const int e0 = blockIdx.x * CHUNK;
    const int e1 = min(e0 + CHUNK, E);
    hcnt[tid] = 0;
    __syncthreads();
    for (int e = e0 + tid; e < e1; e += 256)
        atomicAdd(&hcnt[dst[e] >> BSH], 1);
    __syncthreads();
    {
        int c = hcnt[tid];
        hbase[tid] = (c > 0) ? atomicAdd(&gcur[tid], c) : 0;
        hcnt[tid] = 0;                   // reuse as local cursor
    }
    __syncthreads();
    for (int e = e0 + tid; e < e1; e += 256) {
        int d = dst[e];
        int s = src[e];
        int b = d >> BSH;
        int r = atomicAdd(&hcnt[b], 1);
        int p = hbase[b] + r;
        if (p < CAP) {
            staging[(size_t)b * CAP + p] = (u32)s | ((u32)(d & 255) << 16);
        } else {
            int q = atomicAdd(ovfcur, 1);
            if (q < OVFCAP) ovf[q] = (u32)s | ((u32)d << 16);
        }
    }
}

// Per-bucket counting sort, entirely LDS-cursor based. One block per bucket:
//   hist -> bucket base (reduce gcur) -> local excl scan -> row_start/dinv
//   -> csr fill (LDS cursors) -> scale_x for the bucket's own 256 rows.
// Blocks [nbuck, nbuck+17): weight canonicalization.
// wc layout (u16): [0,8192) W1t[n*64+k] | [8192,16384) W2t[n*128+k]
//                  [16384,16512) b1 | [16512,16576) b2
__global__ __launch_bounds__(256) void k_bucket(
    const u32* __restrict__ staging, const int* __restrict__ gcur,
    const u32* __restrict__ ovf, const int* __restrict__ ovfcur,
    int* __restrict__ row_start, float* __restrict__ dinv,
    u16* __restrict__ csr, int nbuck,
    const void* __restrict__ W1, const void* __restrict__ b1,
    const void* __restrict__ W2, const void* __restrict__ b2,
    u16* __restrict__ wc,
    const void* __restrict__ x, u16* __restrict__ gxt, int N, int E) {
    __shared__ float sflag;
    __shared__ int hcnt[256];
    __shared__ int hscan[256];
    __shared__ int hcur[256];
    __shared__ int sred[256];
    __shared__ int sbase;
    __shared__ float sdinv[256];
    const int bid = blockIdx.x;
    const int tid = threadIdx.x;
    bool isbf = block_isbf((const u16*)x, &sflag);

    if (bid < nbuck) {
        const int b = bid;
        const int used = min(gcur[b], CAP);
        const u32* st = staging + (size_t)b * CAP;
        const int no = min(ovfcur[0], OVFCAP);
        // bucket base = sum gcur[0..b)
        sred[tid] = (tid < b) ? gcur[tid] : 0;
        hcnt[tid] = 0;
        __syncthreads();
        for (int s = 128; s > 0; s >>= 1) {
            if (tid < s) sred[tid] += sred[tid + s];
            __syncthreads();
        }
        if (tid == 0) sbase = sred[0];
        // pass1: per-node hist (staging + overflow)
        for (int i = tid; i < used; i += 256)
            atomicAdd(&hcnt[st[i] >> 16], 1);
        for (int i = tid; i < no; i += 256) {
            u32 pk = ovf[i];
            int d = (int)(pk >> 16);
            if ((d >> BSH) == b) atomicAdd(&hcnt[d & 255], 1);
        }
        __syncthreads();
        // exclusive scan over 256 counts
        int v = hcnt[tid];
        hscan[tid] = v;
        __syncthreads();
        for (int s = 1; s < 256; s <<= 1) {
            int t = (tid >= s) ? hscan[tid - s] : 0;
            __syncthreads();
            hscan[tid] += t;
            __syncthreads();
        }
        int excl = hscan[tid] - v;
        hcur[tid] = excl;
        int base = sbase;
        float dv = rsqrtf((float)(v + 1));
        sdinv[tid] = dv;
        int node = (b << BSH) + tid;
        if (node < N) {
            row_start[node] = base + excl;
            dinv[node] = dv;
        }
        if (b == 0 && tid == 0) row_start[N] = E;
        __syncthreads();
        // pass2: csr fill via LDS cursors (compact 2*CAP-byte csr window)
        for (int i = tid; i < used; i += 256) {
            u32 pk = st[i];
            int r = atomicAdd(&hcur[pk >> 16], 1);
            csr[base + r] = (u16)(pk & 0xFFFFu);
        }
        for (int i = tid; i < no; i += 256) {
            u32 pk = ovf[i];
            int d = (int)(pk >> 16);
            if ((d >> BSH) == b) {
                int r = atomicAdd(&hcur[d & 255], 1);
                csr[base + r] = (u16)(pk & 0xFFFFu);
            }
        }
        // scale_x for our 256 rows: gxt[row] = bf16(x[row] * dinv[row])
        const int row0 = b << BSH;
        for (int i = tid; i < 256 * 16; i += 256) {
            int rl = i >> 4;
            int node2 = row0 + rl;
            if (node2 >= N) break;
            int q = i & 15;
            size_t idx = (size_t)node2 * 16 + q;
            float di = sdinv[rl];
            float4 vv;
            if (isbf) {
                ushort4 u = ((const ushort4*)x)[idx];
                vv.x = bf2f(u.x); vv.y = bf2f(u.y); vv.z = bf2f(u.z); vv.w = bf2f(u.w);
            } else {
                vv = ((const float4*)x)[idx];
            }
            ushort4 o;
            o.x = f2bf(vv.x * di); o.y = f2bf(vv.y * di);
            o.z = f2bf(vv.z * di); o.w = f2bf(vv.w * di);
            ((ushort4*)gxt)[idx] = o;
        }
    } else {
        // weight canonicalize (17 blocks)
        int cb = bid - nbuck;
        for (int i = cb * 256 + tid; i < 16576; i += 17 * 256) {
            const void* s; int off;
            if (i < 8192)       { int nn = i >> 6, k = i & 63;  s = W1; off = k * 128 + nn; }
            else if (i < 16384) { int j = i - 8192; int nn = j >> 7, k = j & 127; s = W2; off = k * 64 + nn; }
            else if (i < 16512) { s = b1; off = i - 16384; }
            else                { s = b2; off = i - 16512; }
            wc[i] = isbf ? ((const u16*)s)[off] : f2bf(((const float*)s)[off]);
        }
    }
}

// gather: out[d] = feat[d] + sum_{j in in(d)} feat[csr[j]]
// 8 lanes per node, uint4 (16 B) loads: 4x bytes-in-flight per vmcnt slot vs u32.
template<bool FINAL>
__global__ __launch_bounds__(256) void k_gather(
    const uint4* __restrict__ feat, const int* __restrict__ row_start,
    const u16* __restrict__ csr, const float* __restrict__ dinv,
    const u16* __restrict__ b2c, const void* __restrict__ xdet,
    void* __restrict__ outp, int n) {
    __shared__ float sflag;
    bool isbf = true;
    if (FINAL) isbf = block_isbf((const u16*)xdet, &sflag);
    int t = blockIdx.x * 256 + threadIdx.x;
    int d = t >> 3;
    int lane = t & 7;            // 8 lanes/node, lane covers feats [8*lane, 8*lane+8)
    if (d >= n) return;
    const uint4* fl = feat + lane;   // row = 8 uint4
    float a[8];
    {
        uint4 w = fl[(size_t)d * 8];     // self-loop
        a[0] = bf2f((u16)(w.x & 0xFFFFu)); a[1] = bf2f((u16)(w.x >> 16));
        a[2] = bf2f((u16)(w.y & 0xFFFFu)); a[3] = bf2f((u16)(w.y >> 16));
        a[4] = bf2f((u16)(w.z & 0xFFFFu)); a[5] = bf2f((u16)(w.z >> 16));
        a[6] = bf2f((u16)(w.w & 0xFFFFu)); a[7] = bf2f((u16)(w.w >> 16));
    }
    int s0 = row_start[d], s1 = row_start[d + 1];
    int deg = s1 - s0;
    int j = s0;
    int end8 = s0 + (deg & ~7);
    for (; j < end8; j += 8) {
        int idx = (int)csr[j + lane];    // 8 indices, one per lane
        uint4 wv[8];
#pragma unroll
        for (int u = 0; u < 8; u++) {
            int sv = __shfl(idx, u, 8);
            wv[u] = fl[(size_t)sv * 8];
        }
#pragma unroll
        for (int u = 0; u < 8; u++) acc8(wv[u], a);
    }
    int rem = s1 - j;
    if (rem > 0) {
        int idx = (lane < rem) ? (int)csr[j + lane] : 0;
        for (int u = 0; u < rem; u++) {
            int sv = __shfl(idx, u, 8);
            uint4 wv = fl[(size_t)sv * 8];
            acc8(wv, a);
        }
    }
    if (FINAL) {
        float di = dinv[d];
#pragma unroll
        for (int u = 0; u < 8; u++)
            a[u] = a[u] * di + bf2f(b2c[8 * lane + u]);
        if (isbf) {
            uint4 o;
            o.x = (u32)f2bf(a[0]) | ((u32)f2bf(a[1]) << 16);
            o.y = (u32)f2bf(a[2]) | ((u32)f2bf(a[3]) << 16);
            o.z = (u32)f2bf(a[4]) | ((u32)f2bf(a[5]) << 16);
            o.w = (u32)f2bf(a[6]) | ((u32)f2bf(a[7]) << 16);
            ((uint4*)outp)[(size_t)d * 8 + lane] = o;
        } else {
            float4* op = (float4*)outp;
            op[(size_t)d * 16 + 2 * lane]     = make_float4(a[0], a[1], a[2], a[3]);
            op[(size_t)d * 16 + 2 * lane + 1] = make_float4(a[4], a[5], a[6], a[7]);
        }
    } else {
        uint4 o;
        o.x = (u32)f2bf(a[0]) | ((u32)f2bf(a[1]) << 16);
        o.y = (u32)f2bf(a[2]) | ((u32)f2bf(a[3]) << 16);
        o.z = (u32)f2bf(a[4]) | ((u32)f2bf(a[5]) << 16);
        o.w = (u32)f2bf(a[6]) | ((u32)f2bf(a[7]) << 16);
        ((uint4*)outp)[(size_t)d * 8 + lane] = o;
    }
}

// MFMA fused 2-layer MLP on a 32-row tile (53 KB LDS -> 3 blocks/CU), in-place safe:
//   h   = relu( bf16(dinv[r]*acc1[r,:]) @ W1 + b1 )   [32 x 128]
//   ht2 = ( h @ W2 ) * dinv[r]                        [32 x 64]  -> bf16 outb
__global__ __launch_bounds__(256) void k_mlp(
    const u16* __restrict__ accin, const u16* __restrict__ wc,
    const float* __restrict__ dinv, u16* outb, int n) {
    __shared__ __align__(16) u16 As[32 * 72];      //  4.5 KB
    __shared__ __align__(16) u16 W1t[128 * 72];    // 18.0 KB
    __shared__ __align__(16) u16 W2t[64 * 136];    // 17.0 KB
    __shared__ __align__(16) u16 Hs[32 * 136];     //  8.5 KB
    __shared__ float b1s[128];
    __shared__ float dvs[32];
    const int tid = threadIdx.x;
    const int row0 = blockIdx.x * 32;

    if (tid < 32) {
        int r = row0 + tid;
        dvs[tid] = (r < n) ? dinv[r] : 0.f;
    } else if (tid < 160) {
        b1s[tid - 32] = bf2f(wc[16384 + tid - 32]);
    }
    for (int i = tid; i < 1024; i += 256) {
        int r = i >> 5, kk = i & 31;
        int row = row0 + r;
        u32 v = 0;
        if (row < n) {
            u32 g = ((const u32*)accin)[(size_t)row * 32 + kk];
            float di = dinv[row];
            u16 lo = f2bf(bf2f((u16)(g & 0xFFFFu)) * di);
            u16 hi = f2bf(bf2f((u16)(g >> 16)) * di);
            v = (u32)lo | ((u32)hi << 16);
        }
        *(u32*)&As[r * 72 + kk * 2] = v;
    }
    for (int i = tid; i < 4096; i += 256) {
        int nn = i >> 5, kk = i & 31;
        *(u32*)&W1t[nn * 72 + kk * 2] = ((const u32*)wc)[i];
    }
    for (int i = tid; i < 4096; i += 256) {
        int nn = i >> 6, kk = i & 63;
        *(u32*)&W2t[nn * 136 + kk * 2] = ((const u32*)wc)[4096 + i];
    }
    __syncthreads();

    const int wave = tid >> 6;     // 0..3
    const int lane = tid & 63;
    const int q = lane >> 4;       // quad
    const int ln = lane & 15;

    // ---- GEMM1: [32x64] @ [64x128] ----
    bf16x8 a[2][2];
#pragma unroll
    for (int mt = 0; mt < 2; mt++)
#pragma unroll
        for (int ks = 0; ks < 2; ks++)
            a[mt][ks] = *(const bf16x8*)&As[(mt * 16 + ln) * 72 + ks * 32 + q * 8];

    f32x4 c1[2][2];   // [ntl][mt]
#pragma unroll
    for (int ntl = 0; ntl < 2; ntl++)
#pragma unroll
        for (int mt = 0; mt < 2; mt++) c1[ntl][mt] = (f32x4){0.f, 0.f, 0.f, 0.f};

#pragma unroll
    for (int ntl = 0; ntl < 2; ntl++) {
        int nt = wave * 2 + ntl;
        bf16x8 b0 = *(const bf16x8*)&W1t[(nt * 16 + ln) * 72 + 0 + q * 8];
        bf16x8 b1f = *(const bf16x8*)&W1t[(nt * 16 + ln) * 72 + 32 + q * 8];
#pragma unroll
        for (int mt = 0; mt < 2; mt++) {
            c1[ntl][mt] = __builtin_amdgcn_mfma_f32_16x16x32_bf16(a[mt][0], b0, c1[ntl][mt], 0, 0, 0);
            c1[ntl][mt] = __builtin_amdgcn_mfma_f32_16x16x32_bf16(a[mt][1], b1f, c1[ntl][mt], 0, 0, 0);
        }
    }
#pragma unroll
    for (int ntl = 0; ntl < 2; ntl++) {
        int col = (wave * 2 + ntl) * 16 + ln;
        float bb = b1s[col];
#pragma unroll
        for (int mt = 0; mt < 2; mt++)
#pragma unroll
            for (int r = 0; r < 4; r++) {
                int hrow = mt * 16 + q * 4 + r;
                Hs[hrow * 136 + col] = f2bf(fmaxf(c1[ntl][mt][r] + bb, 0.f));
            }
    }
    __syncthreads();

    // ---- GEMM2: [32x128] @ [128x64] ----
    f32x4 c2[2];
    c2[0] = (f32x4){0.f, 0.f, 0.f, 0.f};
    c2[1] = (f32x4){0.f, 0.f, 0.f, 0.f};
#pragma unroll
    for (int ks = 0; ks < 4; ks++) {
        bf16x8 bb = *(const bf16x8*)&W2t[(wave * 16 + ln) * 136 + ks * 32 + q * 8];
#pragma unroll
        for (int mt = 0; mt < 2; mt++) {
            bf16x8 aa = *(const bf16x8*)&Hs[(mt * 16 + ln) * 136 + ks * 32 + q * 8];
            c2[mt] = __builtin_amdgcn_mfma_f32_16x16x32_bf16(aa, bb, c2[mt], 0, 0, 0);
        }
    }
#pragma unroll
    for (int mt = 0; mt < 2; mt++)
#pragma unroll
        for (int r = 0; r < 4; r++) {
            int rloc = mt * 16 + q * 4 + r;
            int row = row0 + rloc;
            if (row < n) {
                int col = wave * 16 + ln;
                outb[(size_t)row * 64 + col] = f2bf(c2[mt][r] * dvs[rloc]);
            }
        }
}

extern "C" void kernel_launch(void* const* d_in, const int* in_sizes, int n_in,
                              void* d_out, int out_size, void* d_ws, size_t ws_size,
                              hipStream_t stream) {
    const void* x  = d_in[0];
    const int* ei  = (const int*)d_in[1];
    const void* W1 = d_in[2];
    const void* b1 = d_in[3];
    const void* W2 = d_in[4];
    const void* b2 = d_in[5];

    const int N = in_sizes[0] / 64;   // 50000 (< 65536 required: u16 csr + packing)
    const int E = in_sizes[1] / 2;    // 800000
    const int* src = ei;
    const int* dst = ei + E;

    // workspace (~8.5 MB of d_ws):
    //   dinv[NP] | gcur[256] | ovfcur[+pad 64] | row_start[N+64] | ovf[8192] u32
    //   | csr[E] u16 | wc[16576] u16 | bufB (N*64 u16)
    // staging (nbuck*CAP u32 ~4 MB) aliases bufB (dead until k_mlp writes it).
    // xt lives in d_out (scratch until k_gather<true> rewrites it).
    float* ws = (float*)d_ws;
    const int NP = ((N + 64) + 63) & ~63;
    float* dinv    = ws;
    int* gcur      = (int*)(ws + NP);
    int* ovfcur    = gcur + 256;
    int* row_start = gcur + 320;
    u32* ovf       = (u32*)(row_start + ((N + 64) & ~63));
    u16* csr       = (u16*)(ovf + OVFCAP);
    u16* wc        = (u16*)(((size_t)(csr + E) + 255) & ~(size_t)255);
    u16* bufB      = (u16*)(((size_t)(wc + 16576) + 255) & ~(size_t)255);
    u32* staging   = (u32*)bufB;
    u16* gxt       = (u16*)d_out;

    const int gth = (N * 8 + 255) / 256;       // gather grid (8 lanes/node)
    const int nbuck = (N + 255) >> BSH;        // 196 (<=256 required)
    const int binB = (E + CHUNK - 1) / CHUNK;  // 391
    dim3 blk(256);

    // zero gcur + ovfcur (graph-capture legal)
    hipMemsetAsync(gcur, 0, 320 * sizeof(int), stream);
    // bin edges into per-bucket staging (no per-node atomics)
    k_binA2<<<dim3(binB), blk, 0, stream>>>(src, dst, gcur, staging, ovf, ovfcur, E);
    // per-bucket counting sort (row_start/dinv/csr) + scale_x + weight canon
    k_bucket<<<dim3(nbuck + 17), blk, 0, stream>>>(staging, gcur, ovf, ovfcur,
                                                   row_start, dinv, csr, nbuck,
                                                   W1, b1, W2, b2, wc, x, gxt, N, E);
    // acc1 = gather(xt) -> bufB (staging now dead)
    k_gather<false><<<dim3(gth), blk, 0, stream>>>((const uint4*)gxt, row_start, csr,
                                                   dinv, wc + 16512, x, bufB, N);
    // ht2 = (relu(dinv*acc1 @ W1 + b1) @ W2)*dinv -> bufB (in-place, row-local)
    k_mlp<<<dim3((N + 31) / 32), blk, 0, stream>>>((const u16*)bufB, wc, dinv, bufB, N);
    // out = bf16( (ht2[d]+gather(ht2))*dinv + b2 ) -> d_out
    k_gather<true><<<dim3(gth), blk, 0, stream>>>((const uint4*)bufB, row_start, csr,
                                                  dinv, wc + 16512, x, d_out, N);
}

// Round 12
// 152.760 us; speedup vs baseline: 1.0506x; 1.0506x over previous
//
#include <hip/hip_runtime.h>

typedef unsigned short u16;
typedef unsigned int u32;

typedef __attribute__((ext_vector_type(8))) short bf16x8;
typedef __attribute__((ext_vector_type(4))) float f32x4;

#define BSH 8          // bucket shift: 256 nodes per bucket
#define CAP 5120       // staging capacity per bucket (mean 4081 at E=800k, +16 sigma)
#define OVFCAP 8192
#define CHUNK 2048     // edges per binA2 block (exactly 8 per thread)

__device__ __forceinline__ float bf2f(u16 u) {
    return __uint_as_float(((u32)u) << 16);
}
__device__ __forceinline__ u16 f2bf(float f) {
    u32 x = __float_as_uint(f);
    return (u16)((x + 0x7fffu + ((x >> 16) & 1u)) >> 16);
}

// block-uniform dtype flag: true if x is bf16, false if fp32.
__device__ __forceinline__ bool block_isbf(const u16* __restrict__ x, float* sflag) {
    int tid = threadIdx.x;
    if (tid < 64) {
        u16 v = x[tid * 2];
        u32 ex = (v >> 7) & 0xFFu;
        unsigned long long m = __ballot(ex >= 90u && ex <= 140u);
        if (tid == 0) *sflag = (m == ~0ull) ? 1.0f : 0.0f;
    }
    __syncthreads();
    return *sflag != 0.0f;
}

__device__ __forceinline__ void acc8(uint4 w, float* a) {
    a[0] += bf2f((u16)(w.x & 0xFFFFu)); a[1] += bf2f((u16)(w.x >> 16));
    a[2] += bf2f((u16)(w.y & 0xFFFFu)); a[3] += bf2f((u16)(w.y >> 16));
    a[4] += bf2f((u16)(w.z & 0xFFFFu)); a[5] += bf2f((u16)(w.z >> 16));
    a[6] += bf2f((u16)(w.w & 0xFFFFu)); a[7] += bf2f((u16)(w.w >> 16));
}

// scale+repack: u32 of 2 bf16 -> scaled u32 of 2 bf16
__device__ __forceinline__ u32 scale2(u32 g, float di) {
    u16 lo = f2bf(bf2f((u16)(g & 0xFFFFu)) * di);
    u16 hi = f2bf(bf2f((u16)(g >> 16)) * di);
    return (u32)lo | ((u32)hi << 16);
}

// Bin edges into per-bucket staging. NO per-node atomics; single pass over memory
// (8 edges/thread register-cached). bucket(d) = d >> BSH. Entry: src | (d&255)<<16.
__global__ __launch_bounds__(256) void k_binA2(
    const int* __restrict__ src, const int* __restrict__ dst,
    int* __restrict__ gcur, u32* __restrict__ staging,
    u32* __restrict__ ovf, int* __restrict__ ovfcur, int E) {
    __shared__ int hcnt[256];
    __shared__ int hbase[256];
    const int tid = threadIdx.x;
    const int e0 = blockIdx.x * CHUNK;
    const int e1 = min(e0 + CHUNK, E);
    hcnt[tid] = 0;
    __syncthreads();
    int dl[8], sl[8];
#pragma unroll
    for (int k = 0; k < 8; k++) {
        int e = e0 + tid + k * 256;
        bool ok = e < e1;
        dl[k] = ok ? dst[e] : -1;
        sl[k] = ok ? src[e] : 0;
        if (ok) atomicAdd(&hcnt[dl[k] >> BSH], 1);
    }
    __syncthreads();
    {
        int c = hcnt[tid];
        hbase[tid] = (c > 0) ? atomicAdd(&gcur[tid], c) : 0;
        hcnt[tid] = 0;                   // reuse as local cursor
    }
    __syncthreads();
#pragma unroll
    for (int k = 0; k < 8; k++) {
        int d = dl[k];
        if (d < 0) continue;
        int b = d >> BSH;
        int r = atomicAdd(&hcnt[b], 1);
        int p = hbase[b] + r;
        if (p < CAP) {
            staging[(size_t)b * CAP + p] = (u32)sl[k] | ((u32)(d & 255) << 16);
        } else {
            int q = atomicAdd(ovfcur, 1);
            if (q < OVFCAP) ovf[q] = (u32)sl[k] | ((u32)d << 16);
        }
    }
}

// Per-bucket counting sort, entirely LDS-cursor based. One block per bucket:
//   hist -> bucket base (reduce gcur) -> local excl scan -> row_start/dinv
//   -> csr fill (LDS cursors) -> scale_x for the bucket's own 256 rows.
// Blocks [nbuck, nbuck+17): weight canonicalization.
// wc layout (u16): [0,8192) W1t[n*64+k] | [8192,16384) W2t[n*128+k]
//                  [16384,16512) b1 | [16512,16576) b2
__global__ __launch_bounds__(256) void k_bucket(
    const u32* __restrict__ staging, const int* __restrict__ gcur,
    const u32* __restrict__ ovf, const int* __restrict__ ovfcur,
    int* __restrict__ row_start, float* __restrict__ dinv,
    u16* __restrict__ csr, int nbuck,
    const void* __restrict__ W1, const void* __restrict__ b1,
    const void* __restrict__ W2, const void* __restrict__ b2,
    u16* __restrict__ wc,
    const void* __restrict__ x, u16* __restrict__ gxt, int N, int E) {
    __shared__ float sflag;
    __shared__ int hcnt[256];
    __shared__ int hscan[256];
    __shared__ int hcur[256];
    __shared__ int sred[256];
    __shared__ int sbase;
    __shared__ float sdinv[256];
    const int bid = blockIdx.x;
    const int tid = threadIdx.x;
    bool isbf = block_isbf((const u16*)x, &sflag);

    if (bid < nbuck) {
        const int b = bid;
        const int used = min(gcur[b], CAP);
        const u32* st = staging + (size_t)b * CAP;
        const int no = min(ovfcur[0], OVFCAP);
        const int used4 = used >> 2;
        // bucket base = sum gcur[0..b)
        sred[tid] = (tid < b) ? gcur[tid] : 0;
        hcnt[tid] = 0;
        __syncthreads();
        for (int s = 128; s > 0; s >>= 1) {
            if (tid < s) sred[tid] += sred[tid + s];
            __syncthreads();
        }
        if (tid == 0) sbase = sred[0];
        // pass1: per-node hist (staging uint4-vectorized + overflow)
        for (int i = tid; i < used4; i += 256) {
            uint4 p4 = ((const uint4*)st)[i];
            atomicAdd(&hcnt[p4.x >> 16], 1);
            atomicAdd(&hcnt[p4.y >> 16], 1);
            atomicAdd(&hcnt[p4.z >> 16], 1);
            atomicAdd(&hcnt[p4.w >> 16], 1);
        }
        for (int i = (used4 << 2) + tid; i < used; i += 256)
            atomicAdd(&hcnt[st[i] >> 16], 1);
        for (int i = tid; i < no; i += 256) {
            u32 pk = ovf[i];
            int d = (int)(pk >> 16);
            if ((d >> BSH) == b) atomicAdd(&hcnt[d & 255], 1);
        }
        __syncthreads();
        // exclusive scan over 256 counts
        int v = hcnt[tid];
        hscan[tid] = v;
        __syncthreads();
        for (int s = 1; s < 256; s <<= 1) {
            int t = (tid >= s) ? hscan[tid - s] : 0;
            __syncthreads();
            hscan[tid] += t;
            __syncthreads();
        }
        int excl = hscan[tid] - v;
        hcur[tid] = excl;
        int base = sbase;
        float dv = rsqrtf((float)(v + 1));
        sdinv[tid] = dv;
        int node = (b << BSH) + tid;
        if (node < N) {
            row_start[node] = base + excl;
            dinv[node] = dv;
        }
        if (b == 0 && tid == 0) row_start[N] = E;
        __syncthreads();
        // pass2: csr fill via LDS cursors (uint4-vectorized staging reads)
        for (int i = tid; i < used4; i += 256) {
            uint4 p4 = ((const uint4*)st)[i];
            int r0 = atomicAdd(&hcur[p4.x >> 16], 1); csr[base + r0] = (u16)(p4.x & 0xFFFFu);
            int r1 = atomicAdd(&hcur[p4.y >> 16], 1); csr[base + r1] = (u16)(p4.y & 0xFFFFu);
            int r2 = atomicAdd(&hcur[p4.z >> 16], 1); csr[base + r2] = (u16)(p4.z & 0xFFFFu);
            int r3 = atomicAdd(&hcur[p4.w >> 16], 1); csr[base + r3] = (u16)(p4.w & 0xFFFFu);
        }
        for (int i = (used4 << 2) + tid; i < used; i += 256) {
            u32 pk = st[i];
            int r = atomicAdd(&hcur[pk >> 16], 1);
            csr[base + r] = (u16)(pk & 0xFFFFu);
        }
        for (int i = tid; i < no; i += 256) {
            u32 pk = ovf[i];
            int d = (int)(pk >> 16);
            if ((d >> BSH) == b) {
                int r = atomicAdd(&hcur[d & 255], 1);
                csr[base + r] = (u16)(pk & 0xFFFFu);
            }
        }
        // scale_x for our 256 rows: gxt[row] = bf16(x[row] * dinv[row])
        const int row0 = b << BSH;
        for (int i = tid; i < 256 * 16; i += 256) {
            int rl = i >> 4;
            int node2 = row0 + rl;
            if (node2 >= N) break;
            int q = i & 15;
            size_t idx = (size_t)node2 * 16 + q;
            float di = sdinv[rl];
            float4 vv;
            if (isbf) {
                ushort4 u = ((const ushort4*)x)[idx];
                vv.x = bf2f(u.x); vv.y = bf2f(u.y); vv.z = bf2f(u.z); vv.w = bf2f(u.w);
            } else {
                vv = ((const float4*)x)[idx];
            }
            ushort4 o;
            o.x = f2bf(vv.x * di); o.y = f2bf(vv.y * di);
            o.z = f2bf(vv.z * di); o.w = f2bf(vv.w * di);
            ((ushort4*)gxt)[idx] = o;
        }
    } else {
        // weight canonicalize (17 blocks)
        int cb = bid - nbuck;
        for (int i = cb * 256 + tid; i < 16576; i += 17 * 256) {
            const void* s; int off;
            if (i < 8192)       { int nn = i >> 6, k = i & 63;  s = W1; off = k * 128 + nn; }
            else if (i < 16384) { int j = i - 8192; int nn = j >> 7, k = j & 127; s = W2; off = k * 64 + nn; }
            else if (i < 16512) { s = b1; off = i - 16384; }
            else                { s = b2; off = i - 16512; }
            wc[i] = isbf ? ((const u16*)s)[off] : f2bf(((const float*)s)[off]);
        }
    }
}

// gather: out[d] = feat[d] + sum_{j in in(d)} feat[csr[j]]
// 8 lanes per node, uint4 (16 B) loads.
template<bool FINAL>
__global__ __launch_bounds__(256) void k_gather(
    const uint4* __restrict__ feat, const int* __restrict__ row_start,
    const u16* __restrict__ csr, const float* __restrict__ dinv,
    const u16* __restrict__ b2c, const void* __restrict__ xdet,
    void* __restrict__ outp, int n) {
    __shared__ float sflag;
    bool isbf = true;
    if (FINAL) isbf = block_isbf((const u16*)xdet, &sflag);
    int t = blockIdx.x * 256 + threadIdx.x;
    int d = t >> 3;
    int lane = t & 7;            // 8 lanes/node, lane covers feats [8*lane, 8*lane+8)
    if (d >= n) return;
    const uint4* fl = feat + lane;   // row = 8 uint4
    float a[8];
    {
        uint4 w = fl[(size_t)d * 8];     // self-loop
        a[0] = bf2f((u16)(w.x & 0xFFFFu)); a[1] = bf2f((u16)(w.x >> 16));
        a[2] = bf2f((u16)(w.y & 0xFFFFu)); a[3] = bf2f((u16)(w.y >> 16));
        a[4] = bf2f((u16)(w.z & 0xFFFFu)); a[5] = bf2f((u16)(w.z >> 16));
        a[6] = bf2f((u16)(w.w & 0xFFFFu)); a[7] = bf2f((u16)(w.w >> 16));
    }
    int s0 = row_start[d], s1 = row_start[d + 1];
    int deg = s1 - s0;
    int j = s0;
    int end8 = s0 + (deg & ~7);
    for (; j < end8; j += 8) {
        int idx = (int)csr[j + lane];    // 8 indices, one per lane
        uint4 wv[8];
#pragma unroll
        for (int u = 0; u < 8; u++) {
            int sv = __shfl(idx, u, 8);
            wv[u] = fl[(size_t)sv * 8];
        }
#pragma unroll
        for (int u = 0; u < 8; u++) acc8(wv[u], a);
    }
    int rem = s1 - j;
    if (rem > 0) {
        int idx = (lane < rem) ? (int)csr[j + lane] : 0;
        for (int u = 0; u < rem; u++) {
            int sv = __shfl(idx, u, 8);
            uint4 wv = fl[(size_t)sv * 8];
            acc8(wv, a);
        }
    }
    if (FINAL) {
        float di = dinv[d];
#pragma unroll
        for (int u = 0; u < 8; u++)
            a[u] = a[u] * di + bf2f(b2c[8 * lane + u]);
        if (isbf) {
            uint4 o;
            o.x = (u32)f2bf(a[0]) | ((u32)f2bf(a[1]) << 16);
            o.y = (u32)f2bf(a[2]) | ((u32)f2bf(a[3]) << 16);
            o.z = (u32)f2bf(a[4]) | ((u32)f2bf(a[5]) << 16);
            o.w = (u32)f2bf(a[6]) | ((u32)f2bf(a[7]) << 16);
            ((uint4*)outp)[(size_t)d * 8 + lane] = o;
        } else {
            float4* op = (float4*)outp;
            op[(size_t)d * 16 + 2 * lane]     = make_float4(a[0], a[1], a[2], a[3]);
            op[(size_t)d * 16 + 2 * lane + 1] = make_float4(a[4], a[5], a[6], a[7]);
        }
    } else {
        uint4 o;
        o.x = (u32)f2bf(a[0]) | ((u32)f2bf(a[1]) << 16);
        o.y = (u32)f2bf(a[2]) | ((u32)f2bf(a[3]) << 16);
        o.z = (u32)f2bf(a[4]) | ((u32)f2bf(a[5]) << 16);
        o.w = (u32)f2bf(a[6]) | ((u32)f2bf(a[7]) << 16);
        ((uint4*)outp)[(size_t)d * 8 + lane] = o;
    }
}

// MFMA fused 2-layer MLP on a 32-row tile (53 KB LDS -> 3 blocks/CU), in-place safe:
//   h   = relu( bf16(dinv[r]*acc1[r,:]) @ W1 + b1 )   [32 x 128]
//   ht2 = ( h @ W2 ) * dinv[r]                        [32 x 64]  -> bf16 outb
// All staging uint4-vectorized (LDS rows 16B-aligned: strides 144/272 B).
__global__ __launch_bounds__(256) void k_mlp(
    const u16* __restrict__ accin, const u16* __restrict__ wc,
    const float* __restrict__ dinv, u16* outb, int n) {
    __shared__ __align__(16) u16 As[32 * 72];      //  4.5 KB
    __shared__ __align__(16) u16 W1t[128 * 72];    // 18.0 KB
    __shared__ __align__(16) u16 W2t[64 * 136];    // 17.0 KB
    __shared__ __align__(16) u16 Hs[32 * 136];     //  8.5 KB
    __shared__ float b1s[128];
    __shared__ float dvs[32];
    const int tid = threadIdx.x;
    const int row0 = blockIdx.x * 32;

    if (tid < 32) {
        int r = row0 + tid;
        dvs[tid] = (r < n) ? dinv[r] : 0.f;
    } else if (tid < 160) {
        b1s[tid - 32] = bf2f(wc[16384 + tid - 32]);
    }
    // As: 32 rows x 8 uint4 (8 feats each) = 256 uint4; scale by dinv, re-round
    {
        int i = tid;                       // exactly one per thread
        int r = i >> 3, kk = i & 7;
        int row = row0 + r;
        uint4 v = make_uint4(0, 0, 0, 0);
        if (row < n) {
            uint4 g = ((const uint4*)accin)[(size_t)row * 8 + kk];
            float di = dinv[row];
            v.x = scale2(g.x, di); v.y = scale2(g.y, di);
            v.z = scale2(g.z, di); v.w = scale2(g.w, di);
        }
        *(uint4*)&As[r * 72 + kk * 8] = v;
    }
    // W1t: 128 rows x 8 uint4, LDS row stride 72 u16 (144 B)
    for (int i = tid; i < 1024; i += 256) {
        int nn = i >> 3, kk = i & 7;
        *(uint4*)&W1t[nn * 72 + kk * 8] = ((const uint4*)wc)[i];
    }
    // W2t: 64 rows x 16 uint4, LDS row stride 136 u16 (272 B)
    for (int i = tid; i < 1024; i += 256) {
        int nn = i >> 4, kk = i & 15;
        *(uint4*)&W2t[nn * 136 + kk * 8] = ((const uint4*)(wc + 8192))[i];
    }
    __syncthreads();

    const int wave = tid >> 6;     // 0..3
    const int lane = tid & 63;
    const int q = lane >> 4;       // quad
    const int ln = lane & 15;

    // ---- GEMM1: [32x64] @ [64x128] ----
    bf16x8 a[2][2];
#pragma unroll
    for (int mt = 0; mt < 2; mt++)
#pragma unroll
        for (int ks = 0; ks < 2; ks++)
            a[mt][ks] = *(const bf16x8*)&As[(mt * 16 + ln) * 72 + ks * 32 + q * 8];

    f32x4 c1[2][2];   // [ntl][mt]
#pragma unroll
    for (int ntl = 0; ntl < 2; ntl++)
#pragma unroll
        for (int mt = 0; mt < 2; mt++) c1[ntl][mt] = (f32x4){0.f, 0.f, 0.f, 0.f};

#pragma unroll
    for (int ntl = 0; ntl < 2; ntl++) {
        int nt = wave * 2 + ntl;
        bf16x8 b0 = *(const bf16x8*)&W1t[(nt * 16 + ln) * 72 + 0 + q * 8];
        bf16x8 b1f = *(const bf16x8*)&W1t[(nt * 16 + ln) * 72 + 32 + q * 8];
#pragma unroll
        for (int mt = 0; mt < 2; mt++) {
            c1[ntl][mt] = __builtin_amdgcn_mfma_f32_16x16x32_bf16(a[mt][0], b0, c1[ntl][mt], 0, 0, 0);
            c1[ntl][mt] = __builtin_amdgcn_mfma_f32_16x16x32_bf16(a[mt][1], b1f, c1[ntl][mt], 0, 0, 0);
        }
    }
#pragma unroll
    for (int ntl = 0; ntl < 2; ntl++) {
        int col = (wave * 2 + ntl) * 16 + ln;
        float bb = b1s[col];
#pragma unroll
        for (int mt = 0; mt < 2; mt++)
#pragma unroll
            for (int r = 0; r < 4; r++) {
                int hrow = mt * 16 + q * 4 + r;
                Hs[hrow * 136 + col] = f2bf(fmaxf(c1[ntl][mt][r] + bb, 0.f));
            }
    }
    __syncthreads();

    // ---- GEMM2: [32x128] @ [128x64] ----
    f32x4 c2[2];
    c2[0] = (f32x4){0.f, 0.f, 0.f, 0.f};
    c2[1] = (f32x4){0.f, 0.f, 0.f, 0.f};
#pragma unroll
    for (int ks = 0; ks < 4; ks++) {
        bf16x8 bb = *(const bf16x8*)&W2t[(wave * 16 + ln) * 136 + ks * 32 + q * 8];
#pragma unroll
        for (int mt = 0; mt < 2; mt++) {
            bf16x8 aa = *(const bf16x8*)&Hs[(mt * 16 + ln) * 136 + ks * 32 + q * 8];
            c2[mt] = __builtin_amdgcn_mfma_f32_16x16x32_bf16(aa, bb, c2[mt], 0, 0, 0);
        }
    }
#pragma unroll
    for (int mt = 0; mt < 2; mt++)
#pragma unroll
        for (int r = 0; r < 4; r++) {
            int rloc = mt * 16 + q * 4 + r;
            int row = row0 + rloc;
            if (row < n) {
                int col = wave * 16 + ln;
                outb[(size_t)row * 64 + col] = f2bf(c2[mt][r] * dvs[rloc]);
            }
        }
}

extern "C" void kernel_launch(void* const* d_in, const int* in_sizes, int n_in,
                              void* d_out, int out_size, void* d_ws, size_t ws_size,
                              hipStream_t stream) {
    const void* x  = d_in[0];
    const int* ei  = (const int*)d_in[1];
    const void* W1 = d_in[2];
    const void* b1 = d_in[3];
    const void* W2 = d_in[4];
    const void* b2 = d_in[5];

    const int N = in_sizes[0] / 64;   // 50000 (< 65536 required: u16 csr + packing)
    const int E = in_sizes[1] / 2;    // 800000
    const int* src = ei;
    const int* dst = ei + E;

    // workspace (~8.5 MB of d_ws):
    //   dinv[NP] | gcur[256] | ovfcur[+pad 64] | row_start[N+64] | ovf[8192] u32
    //   | csr[E] u16 | wc[16576] u16 | bufB (N*64 u16)
    // staging (nbuck*CAP u32 ~4 MB) aliases bufB (dead until k_mlp writes it).
    // xt lives in d_out (scratch until k_gather<true> rewrites it).
    float* ws = (float*)d_ws;
    const int NP = ((N + 64) + 63) & ~63;
    float* dinv    = ws;
    int* gcur      = (int*)(ws + NP);
    int* ovfcur    = gcur + 256;
    int* row_start = gcur + 320;
    u32* ovf       = (u32*)(row_start + ((N + 64) & ~63));
    u16* csr       = (u16*)(ovf + OVFCAP);
    u16* wc        = (u16*)(((size_t)(csr + E) + 255) & ~(size_t)255);
    u16* bufB      = (u16*)(((size_t)(wc + 16576) + 255) & ~(size_t)255);
    u32* staging   = (u32*)bufB;
    u16* gxt       = (u16*)d_out;

    const int gth = (N * 8 + 255) / 256;       // gather grid (8 lanes/node)
    const int nbuck = (N + 255) >> BSH;        // 196 (<=256 required)
    const int binB = (E + CHUNK - 1) / CHUNK;  // 391
    dim3 blk(256);

    // zero gcur + ovfcur (graph-capture legal)
    hipMemsetAsync(gcur, 0, 320 * sizeof(int), stream);
    // bin edges into per-bucket staging (no per-node atomics, single-pass)
    k_binA2<<<dim3(binB), blk, 0, stream>>>(src, dst, gcur, staging, ovf, ovfcur, E);
    // per-bucket counting sort (row_start/dinv/csr) + scale_x + weight canon
    k_bucket<<<dim3(nbuck + 17), blk, 0, stream>>>(staging, gcur, ovf, ovfcur,
                                                   row_start, dinv, csr, nbuck,
                                                   W1, b1, W2, b2, wc, x, gxt, N, E);
    // acc1 = gather(xt) -> bufB (staging now dead)
    k_gather<false><<<dim3(gth), blk, 0, stream>>>((const uint4*)gxt, row_start, csr,
                                                   dinv, wc + 16512, x, bufB, N);
    // ht2 = (relu(dinv*acc1 @ W1 + b1) @ W2)*dinv -> bufB (in-place, row-local)
    k_mlp<<<dim3((N + 31) / 32), blk, 0, stream>>>((const u16*)bufB, wc, dinv, bufB, N);
    // out = bf16( (ht2[d]+gather(ht2))*dinv + b2 ) -> d_out
    k_gather<true><<<dim3(gth), blk, 0, stream>>>((const uint4*)bufB, row_start, csr,
                                                  dinv, wc + 16512, x, d_out, N);
}

// Round 13
// 147.674 us; speedup vs baseline: 1.0868x; 1.0344x over previous
//
#include <hip/hip_runtime.h>

typedef unsigned short u16;
typedef unsigned int u32;

typedef __attribute__((ext_vector_type(8))) short bf16x8;
typedef __attribute__((ext_vector_type(4))) float f32x4;

#define BSH 8          // bucket shift: 256 nodes per bucket
#define CAP 5120       // staging capacity per bucket (mean 4081 at E=800k, +16 sigma)
#define OVFCAP 8192
#define CHUNK 2048     // edges per binA2 block (exactly 8 per thread)

__device__ __forceinline__ float bf2f(u16 u) {
    return __uint_as_float(((u32)u) << 16);
}
__device__ __forceinline__ u16 f2bf(float f) {
    u32 x = __float_as_uint(f);
    return (u16)((x + 0x7fffu + ((x >> 16) & 1u)) >> 16);
}

// block-uniform dtype flag: true if x is bf16, false if fp32.
__device__ __forceinline__ bool block_isbf(const u16* __restrict__ x, float* sflag) {
    int tid = threadIdx.x;
    if (tid < 64) {
        u16 v = x[tid * 2];
        u32 ex = (v >> 7) & 0xFFu;
        unsigned long long m = __ballot(ex >= 90u && ex <= 140u);
        if (tid == 0) *sflag = (m == ~0ull) ? 1.0f : 0.0f;
    }
    __syncthreads();
    return *sflag != 0.0f;
}

__device__ __forceinline__ void acc8(uint4 w, float* a) {
    a[0] += bf2f((u16)(w.x & 0xFFFFu)); a[1] += bf2f((u16)(w.x >> 16));
    a[2] += bf2f((u16)(w.y & 0xFFFFu)); a[3] += bf2f((u16)(w.y >> 16));
    a[4] += bf2f((u16)(w.z & 0xFFFFu)); a[5] += bf2f((u16)(w.z >> 16));
    a[6] += bf2f((u16)(w.w & 0xFFFFu)); a[7] += bf2f((u16)(w.w >> 16));
}

// scale+repack: u32 of 2 bf16 -> scaled u32 of 2 bf16
__device__ __forceinline__ u32 scale2(u32 g, float di) {
    u16 lo = f2bf(bf2f((u16)(g & 0xFFFFu)) * di);
    u16 hi = f2bf(bf2f((u16)(g >> 16)) * di);
    return (u32)lo | ((u32)hi << 16);
}

// Bin edges into per-bucket staging. NO per-node atomics; single pass, int4 loads.
// bucket(d) = d >> BSH. Entry: src | (d&255)<<16.
__global__ __launch_bounds__(256) void k_binA2(
    const int* __restrict__ src, const int* __restrict__ dst,
    int* __restrict__ gcur, u32* __restrict__ staging,
    u32* __restrict__ ovf, int* __restrict__ ovfcur, int E) {
    __shared__ int hcnt[256];
    __shared__ int hbase[256];
    const int tid = threadIdx.x;
    const int e0 = blockIdx.x * CHUNK;
    const int e1 = min(e0 + CHUNK, E);
    hcnt[tid] = 0;
    __syncthreads();
    int dl[8], sl[8];
    const int eb = e0 + tid * 8;
    const bool vec = (eb + 7 < e1) &&
                     ((((size_t)(dst + eb)) | ((size_t)(src + eb))) & 15) == 0;
    if (vec) {
        int4 d0 = ((const int4*)(dst + eb))[0];
        int4 d1 = ((const int4*)(dst + eb))[1];
        int4 s0v = ((const int4*)(src + eb))[0];
        int4 s1v = ((const int4*)(src + eb))[1];
        dl[0] = d0.x; dl[1] = d0.y; dl[2] = d0.z; dl[3] = d0.w;
        dl[4] = d1.x; dl[5] = d1.y; dl[6] = d1.z; dl[7] = d1.w;
        sl[0] = s0v.x; sl[1] = s0v.y; sl[2] = s0v.z; sl[3] = s0v.w;
        sl[4] = s1v.x; sl[5] = s1v.y; sl[6] = s1v.z; sl[7] = s1v.w;
    } else {
#pragma unroll
        for (int k = 0; k < 8; k++) {
            int e = eb + k;
            bool ok = e < e1;
            dl[k] = ok ? dst[e] : -1;
            sl[k] = ok ? src[e] : 0;
        }
    }
#pragma unroll
    for (int k = 0; k < 8; k++)
        if (dl[k] >= 0) atomicAdd(&hcnt[dl[k] >> BSH], 1);
    __syncthreads();
    {
        int c = hcnt[tid];
        hbase[tid] = (c > 0) ? atomicAdd(&gcur[tid], c) : 0;
        hcnt[tid] = 0;                   // reuse as local cursor
    }
    __syncthreads();
#pragma unroll
    for (int k = 0; k < 8; k++) {
        int d = dl[k];
        if (d < 0) continue;
        int b = d >> BSH;
        int r = atomicAdd(&hcnt[b], 1);
        int p = hbase[b] + r;
        if (p < CAP) {
            staging[(size_t)b * CAP + p] = (u32)sl[k] | ((u32)(d & 255) << 16);
        } else {
            int q = atomicAdd(ovfcur, 1);
            if (q < OVFCAP) ovf[q] = (u32)sl[k] | ((u32)d << 16);
        }
    }
}

// Per-bucket counting sort, entirely LDS-cursor based. One block per bucket:
//   hist -> bucket base (reduce gcur) -> local excl scan -> row_start/dinv
//   -> csr fill (LDS cursors) -> scale_x for the bucket's own 256 rows.
// Blocks [nbuck, nbuck+17): weight canonicalization.
// wc layout (u16): [0,8192) W1t[n*64+k] | [8192,16384) W2t[n*128+k]
//                  [16384,16512) b1 | [16512,16576) b2
__global__ __launch_bounds__(256) void k_bucket(
    const u32* __restrict__ staging, const int* __restrict__ gcur,
    const u32* __restrict__ ovf, const int* __restrict__ ovfcur,
    int* __restrict__ row_start, float* __restrict__ dinv,
    u16* __restrict__ csr, int nbuck,
    const void* __restrict__ W1, const void* __restrict__ b1,
    const void* __restrict__ W2, const void* __restrict__ b2,
    u16* __restrict__ wc,
    const void* __restrict__ x, u16* __restrict__ gxt, int N, int E) {
    __shared__ float sflag;
    __shared__ int hcnt[256];
    __shared__ int hscan[256];
    __shared__ int hcur[256];
    __shared__ int sred[256];
    __shared__ int sbase;
    __shared__ float sdinv[256];
    const int bid = blockIdx.x;
    const int tid = threadIdx.x;
    bool isbf = block_isbf((const u16*)x, &sflag);

    if (bid < nbuck) {
        const int b = bid;
        const int used = min(gcur[b], CAP);
        const u32* st = staging + (size_t)b * CAP;
        const int no = min(ovfcur[0], OVFCAP);
        const int used4 = used >> 2;
        // bucket base = sum gcur[0..b)
        sred[tid] = (tid < b) ? gcur[tid] : 0;
        hcnt[tid] = 0;
        __syncthreads();
        for (int s = 128; s > 0; s >>= 1) {
            if (tid < s) sred[tid] += sred[tid + s];
            __syncthreads();
        }
        if (tid == 0) sbase = sred[0];
        // pass1: per-node hist (staging uint4-vectorized + overflow)
        for (int i = tid; i < used4; i += 256) {
            uint4 p4 = ((const uint4*)st)[i];
            atomicAdd(&hcnt[p4.x >> 16], 1);
            atomicAdd(&hcnt[p4.y >> 16], 1);
            atomicAdd(&hcnt[p4.z >> 16], 1);
            atomicAdd(&hcnt[p4.w >> 16], 1);
        }
        for (int i = (used4 << 2) + tid; i < used; i += 256)
            atomicAdd(&hcnt[st[i] >> 16], 1);
        for (int i = tid; i < no; i += 256) {
            u32 pk = ovf[i];
            int d = (int)(pk >> 16);
            if ((d >> BSH) == b) atomicAdd(&hcnt[d & 255], 1);
        }
        __syncthreads();
        // exclusive scan over 256 counts
        int v = hcnt[tid];
        hscan[tid] = v;
        __syncthreads();
        for (int s = 1; s < 256; s <<= 1) {
            int t = (tid >= s) ? hscan[tid - s] : 0;
            __syncthreads();
            hscan[tid] += t;
            __syncthreads();
        }
        int excl = hscan[tid] - v;
        hcur[tid] = excl;
        int base = sbase;
        float dv = rsqrtf((float)(v + 1));
        sdinv[tid] = dv;
        int node = (b << BSH) + tid;
        if (node < N) {
            row_start[node] = base + excl;
            dinv[node] = dv;
        }
        if (b == 0 && tid == 0) row_start[N] = E;
        __syncthreads();
        // pass2: csr fill via LDS cursors (uint4-vectorized staging reads)
        for (int i = tid; i < used4; i += 256) {
            uint4 p4 = ((const uint4*)st)[i];
            int r0 = atomicAdd(&hcur[p4.x >> 16], 1); csr[base + r0] = (u16)(p4.x & 0xFFFFu);
            int r1 = atomicAdd(&hcur[p4.y >> 16], 1); csr[base + r1] = (u16)(p4.y & 0xFFFFu);
            int r2 = atomicAdd(&hcur[p4.z >> 16], 1); csr[base + r2] = (u16)(p4.z & 0xFFFFu);
            int r3 = atomicAdd(&hcur[p4.w >> 16], 1); csr[base + r3] = (u16)(p4.w & 0xFFFFu);
        }
        for (int i = (used4 << 2) + tid; i < used; i += 256) {
            u32 pk = st[i];
            int r = atomicAdd(&hcur[pk >> 16], 1);
            csr[base + r] = (u16)(pk & 0xFFFFu);
        }
        for (int i = tid; i < no; i += 256) {
            u32 pk = ovf[i];
            int d = (int)(pk >> 16);
            if ((d >> BSH) == b) {
                int r = atomicAdd(&hcur[d & 255], 1);
                csr[base + r] = (u16)(pk & 0xFFFFu);
            }
        }
        // scale_x for our 256 rows: gxt[row] = bf16(x[row] * dinv[row])
        const int row0 = b << BSH;
        for (int i = tid; i < 256 * 16; i += 256) {
            int rl = i >> 4;
            int node2 = row0 + rl;
            if (node2 >= N) break;
            int q = i & 15;
            size_t idx = (size_t)node2 * 16 + q;
            float di = sdinv[rl];
            float4 vv;
            if (isbf) {
                ushort4 u = ((const ushort4*)x)[idx];
                vv.x = bf2f(u.x); vv.y = bf2f(u.y); vv.z = bf2f(u.z); vv.w = bf2f(u.w);
            } else {
                vv = ((const float4*)x)[idx];
            }
            ushort4 o;
            o.x = f2bf(vv.x * di); o.y = f2bf(vv.y * di);
            o.z = f2bf(vv.z * di); o.w = f2bf(vv.w * di);
            ((ushort4*)gxt)[idx] = o;
        }
    } else {
        // weight canonicalize (17 blocks)
        int cb = bid - nbuck;
        for (int i = cb * 256 + tid; i < 16576; i += 17 * 256) {
            const void* s; int off;
            if (i < 8192)       { int nn = i >> 6, k = i & 63;  s = W1; off = k * 128 + nn; }
            else if (i < 16384) { int j = i - 8192; int nn = j >> 7, k = j & 127; s = W2; off = k * 64 + nn; }
            else if (i < 16512) { s = b1; off = i - 16384; }
            else                { s = b2; off = i - 16512; }
            wc[i] = isbf ? ((const u16*)s)[off] : f2bf(((const float*)s)[off]);
        }
    }
}

// gather: out[d] = feat[d] + sum_{j in in(d)} feat[csr[j]]
// 8 lanes per node, uint4 loads; csr indices software-pipelined (next batch
// loaded before accumulating current -> csr latency overlaps feat loads).
template<bool FINAL>
__global__ __launch_bounds__(256) void k_gather(
    const uint4* __restrict__ feat, const int* __restrict__ row_start,
    const u16* __restrict__ csr, const float* __restrict__ dinv,
    const u16* __restrict__ b2c, const void* __restrict__ xdet,
    void* __restrict__ outp, int n) {
    __shared__ float sflag;
    bool isbf = true;
    if (FINAL) isbf = block_isbf((const u16*)xdet, &sflag);
    int t = blockIdx.x * 256 + threadIdx.x;
    int d = t >> 3;
    int lane = t & 7;            // 8 lanes/node, lane covers feats [8*lane, 8*lane+8)
    if (d >= n) return;
    const uint4* fl = feat + lane;   // row = 8 uint4
    float a[8];
    {
        uint4 w = fl[(size_t)d * 8];     // self-loop
        a[0] = bf2f((u16)(w.x & 0xFFFFu)); a[1] = bf2f((u16)(w.x >> 16));
        a[2] = bf2f((u16)(w.y & 0xFFFFu)); a[3] = bf2f((u16)(w.y >> 16));
        a[4] = bf2f((u16)(w.z & 0xFFFFu)); a[5] = bf2f((u16)(w.z >> 16));
        a[6] = bf2f((u16)(w.w & 0xFFFFu)); a[7] = bf2f((u16)(w.w >> 16));
    }
    int s0 = row_start[d], s1 = row_start[d + 1];
    int j = s0;
    int cur = (j + lane < s1) ? (int)csr[j + lane] : 0;
    while (j + 8 <= s1) {
        int nxt = (j + 8 + lane < s1) ? (int)csr[j + 8 + lane] : 0;
        uint4 wv[8];
#pragma unroll
        for (int u = 0; u < 8; u++) {
            int sv = __shfl(cur, u, 8);
            wv[u] = fl[(size_t)sv * 8];
        }
#pragma unroll
        for (int u = 0; u < 8; u++) acc8(wv[u], a);
        cur = nxt;
        j += 8;
    }
    int rem = s1 - j;
    if (rem > 0) {
        for (int u = 0; u < rem; u++) {
            int sv = __shfl(cur, u, 8);
            uint4 wv = fl[(size_t)sv * 8];
            acc8(wv, a);
        }
    }
    if (FINAL) {
        float di = dinv[d];
#pragma unroll
        for (int u = 0; u < 8; u++)
            a[u] = a[u] * di + bf2f(b2c[8 * lane + u]);
        if (isbf) {
            uint4 o;
            o.x = (u32)f2bf(a[0]) | ((u32)f2bf(a[1]) << 16);
            o.y = (u32)f2bf(a[2]) | ((u32)f2bf(a[3]) << 16);
            o.z = (u32)f2bf(a[4]) | ((u32)f2bf(a[5]) << 16);
            o.w = (u32)f2bf(a[6]) | ((u32)f2bf(a[7]) << 16);
            ((uint4*)outp)[(size_t)d * 8 + lane] = o;
        } else {
            float4* op = (float4*)outp;
            op[(size_t)d * 16 + 2 * lane]     = make_float4(a[0], a[1], a[2], a[3]);
            op[(size_t)d * 16 + 2 * lane + 1] = make_float4(a[4], a[5], a[6], a[7]);
        }
    } else {
        uint4 o;
        o.x = (u32)f2bf(a[0]) | ((u32)f2bf(a[1]) << 16);
        o.y = (u32)f2bf(a[2]) | ((u32)f2bf(a[3]) << 16);
        o.z = (u32)f2bf(a[4]) | ((u32)f2bf(a[5]) << 16);
        o.w = (u32)f2bf(a[6]) | ((u32)f2bf(a[7]) << 16);
        ((uint4*)outp)[(size_t)d * 8 + lane] = o;
    }
}

// MFMA fused 2-layer MLP on a 64-row tile (61 KB LDS -> 2 blocks/CU), in-place safe:
//   h   = relu( bf16(dinv[r]*acc1[r,:]) @ W1 + b1 )   [64 x 128]
//   ht2 = ( h @ W2 ) * dinv[r]                        [64 x 64]  -> bf16 outb
// 64-row tile halves per-row weight-staging traffic vs 32-row (50 -> 25 MB).
__global__ __launch_bounds__(256) void k_mlp(
    const u16* __restrict__ accin, const u16* __restrict__ wc,
    const float* __restrict__ dinv, u16* outb, int n) {
    __shared__ __align__(16) u16 As[64 * 72];      //  9.0 KB
    __shared__ __align__(16) u16 W1t[128 * 72];    // 18.0 KB
    __shared__ __align__(16) u16 W2t[64 * 136];    // 17.0 KB
    __shared__ __align__(16) u16 Hs[64 * 136];     // 17.0 KB
    __shared__ float b1s[128];
    __shared__ float dvs[64];
    const int tid = threadIdx.x;
    const int row0 = blockIdx.x * 64;

    if (tid < 64) {
        int r = row0 + tid;
        dvs[tid] = (r < n) ? dinv[r] : 0.f;
    } else if (tid < 192) {
        b1s[tid - 64] = bf2f(wc[16384 + tid - 64]);
    }
    // As: 64 rows x 8 uint4; scale by dinv, re-round
    for (int i = tid; i < 512; i += 256) {
        int r = i >> 3, kk = i & 7;
        int row = row0 + r;
        uint4 v = make_uint4(0, 0, 0, 0);
        if (row < n) {
            uint4 g = ((const uint4*)accin)[(size_t)row * 8 + kk];
            float di = dinv[row];
            v.x = scale2(g.x, di); v.y = scale2(g.y, di);
            v.z = scale2(g.z, di); v.w = scale2(g.w, di);
        }
        *(uint4*)&As[r * 72 + kk * 8] = v;
    }
    // W1t: 128 rows x 8 uint4, LDS row stride 72 u16 (144 B)
    for (int i = tid; i < 1024; i += 256) {
        int nn = i >> 3, kk = i & 7;
        *(uint4*)&W1t[nn * 72 + kk * 8] = ((const uint4*)wc)[i];
    }
    // W2t: 64 rows x 16 uint4, LDS row stride 136 u16 (272 B)
    for (int i = tid; i < 1024; i += 256) {
        int nn = i >> 4, kk = i & 15;
        *(uint4*)&W2t[nn * 136 + kk * 8] = ((const uint4*)(wc + 8192))[i];
    }
    __syncthreads();

    const int wave = tid >> 6;     // 0..3
    const int lane = tid & 63;
    const int q = lane >> 4;       // quad
    const int ln = lane & 15;

    // ---- GEMM1: [64x64] @ [64x128] ----
    bf16x8 a[4][2];
#pragma unroll
    for (int mt = 0; mt < 4; mt++)
#pragma unroll
        for (int ks = 0; ks < 2; ks++)
            a[mt][ks] = *(const bf16x8*)&As[(mt * 16 + ln) * 72 + ks * 32 + q * 8];

    f32x4 c1[2][4];   // [ntl][mt]
#pragma unroll
    for (int ntl = 0; ntl < 2; ntl++)
#pragma unroll
        for (int mt = 0; mt < 4; mt++) c1[ntl][mt] = (f32x4){0.f, 0.f, 0.f, 0.f};

#pragma unroll
    for (int ntl = 0; ntl < 2; ntl++) {
        int nt = wave * 2 + ntl;
        bf16x8 b0 = *(const bf16x8*)&W1t[(nt * 16 + ln) * 72 + 0 + q * 8];
        bf16x8 b1f = *(const bf16x8*)&W1t[(nt * 16 + ln) * 72 + 32 + q * 8];
#pragma unroll
        for (int mt = 0; mt < 4; mt++) {
            c1[ntl][mt] = __builtin_amdgcn_mfma_f32_16x16x32_bf16(a[mt][0], b0, c1[ntl][mt], 0, 0, 0);
            c1[ntl][mt] = __builtin_amdgcn_mfma_f32_16x16x32_bf16(a[mt][1], b1f, c1[ntl][mt], 0, 0, 0);
        }
    }
#pragma unroll
    for (int ntl = 0; ntl < 2; ntl++) {
        int col = (wave * 2 + ntl) * 16 + ln;
        float bb = b1s[col];
#pragma unroll
        for (int mt = 0; mt < 4; mt++)
#pragma unroll
            for (int r = 0; r < 4; r++) {
                int hrow = mt * 16 + q * 4 + r;
                Hs[hrow * 136 + col] = f2bf(fmaxf(c1[ntl][mt][r] + bb, 0.f));
            }
    }
    __syncthreads();

    // ---- GEMM2: [64x128] @ [128x64] ----
    f32x4 c2[4];
#pragma unroll
    for (int mt = 0; mt < 4; mt++) c2[mt] = (f32x4){0.f, 0.f, 0.f, 0.f};
#pragma unroll
    for (int ks = 0; ks < 4; ks++) {
        bf16x8 bb = *(const bf16x8*)&W2t[(wave * 16 + ln) * 136 + ks * 32 + q * 8];
#pragma unroll
        for (int mt = 0; mt < 4; mt++) {
            bf16x8 aa = *(const bf16x8*)&Hs[(mt * 16 + ln) * 136 + ks * 32 + q * 8];
            c2[mt] = __builtin_amdgcn_mfma_f32_16x16x32_bf16(aa, bb, c2[mt], 0, 0, 0);
        }
    }
#pragma unroll
    for (int mt = 0; mt < 4; mt++)
#pragma unroll
        for (int r = 0; r < 4; r++) {
            int rloc = mt * 16 + q * 4 + r;
            int row = row0 + rloc;
            if (row < n) {
                int col = wave * 16 + ln;
                outb[(size_t)row * 64 + col] = f2bf(c2[mt][r] * dvs[rloc]);
            }
        }
}

extern "C" void kernel_launch(void* const* d_in, const int* in_sizes, int n_in,
                              void* d_out, int out_size, void* d_ws, size_t ws_size,
                              hipStream_t stream) {
    const void* x  = d_in[0];
    const int* ei  = (const int*)d_in[1];
    const void* W1 = d_in[2];
    const void* b1 = d_in[3];
    const void* W2 = d_in[4];
    const void* b2 = d_in[5];

    const int N = in_sizes[0] / 64;   // 50000 (< 65536 required: u16 csr + packing)
    const int E = in_sizes[1] / 2;    // 800000
    const int* src = ei;
    const int* dst = ei + E;

    // workspace (~8.5 MB of d_ws):
    //   dinv[NP] | gcur[256] | ovfcur[+pad 64] | row_start[N+64] | ovf[8192] u32
    //   | csr[E] u16 | wc[16576] u16 | bufB (N*64 u16)
    // staging (nbuck*CAP u32 ~4 MB) aliases bufB (dead until k_mlp writes it).
    // xt lives in d_out (scratch until k_gather<true> rewrites it).
    float* ws = (float*)d_ws;
    const int NP = ((N + 64) + 63) & ~63;
    float* dinv    = ws;
    int* gcur      = (int*)(ws + NP);
    int* ovfcur    = gcur + 256;
    int* row_start = gcur + 320;
    u32* ovf       = (u32*)(row_start + ((N + 64) & ~63));
    u16* csr       = (u16*)(ovf + OVFCAP);
    u16* wc        = (u16*)(((size_t)(csr + E) + 255) & ~(size_t)255);
    u16* bufB      = (u16*)(((size_t)(wc + 16576) + 255) & ~(size_t)255);
    u32* staging   = (u32*)bufB;
    u16* gxt       = (u16*)d_out;

    const int gth = (N * 8 + 255) / 256;       // gather grid (8 lanes/node)
    const int nbuck = (N + 255) >> BSH;        // 196 (<=256 required)
    const int binB = (E + CHUNK - 1) / CHUNK;  // 391
    dim3 blk(256);

    // zero gcur + ovfcur (graph-capture legal)
    hipMemsetAsync(gcur, 0, 320 * sizeof(int), stream);
    // bin edges into per-bucket staging (no per-node atomics, single-pass, int4)
    k_binA2<<<dim3(binB), blk, 0, stream>>>(src, dst, gcur, staging, ovf, ovfcur, E);
    // per-bucket counting sort (row_start/dinv/csr) + scale_x + weight canon
    k_bucket<<<dim3(nbuck + 17), blk, 0, stream>>>(staging, gcur, ovf, ovfcur,
                                                   row_start, dinv, csr, nbuck,
                                                   W1, b1, W2, b2, wc, x, gxt, N, E);
    // acc1 = gather(xt) -> bufB (staging now dead)
    k_gather<false><<<dim3(gth), blk, 0, stream>>>((const uint4*)gxt, row_start, csr,
                                                   dinv, wc + 16512, x, bufB, N);
    // ht2 = (relu(dinv*acc1 @ W1 + b1) @ W2)*dinv -> bufB (in-place, row-local)
    k_mlp<<<dim3((N + 63) / 64), blk, 0, stream>>>((const u16*)bufB, wc, dinv, bufB, N);
    // out = bf16( (ht2[d]+gather(ht2))*dinv + b2 ) -> d_out
    k_gather<true><<<dim3(gth), blk, 0, stream>>>((const uint4*)bufB, row_start, csr,
                                                  dinv, wc + 16512, x, d_out, N);
}